// Round 1
// baseline (631.559 us; speedup 1.0000x reference)
//
#include <hip/hip_runtime.h>
#include <math.h>

#define BATCH 2
#define SEQ 2048
#define BL (BATCH * SEQ)      // 4096
#define EMBED 1024
#define PROJ 512
#define NHEADS 8
#define HDIM 64

// ---------------------------------------------------------------------------
// Tiled fp32 GEMM: C[M][N] = op(A[M][K] @ B[K][N] (+ bias))
// 64x64 block tile, 256 threads, 4x4 micro-tile per thread, K-step 16.
// Requires M,N % 64 == 0 and K % 16 == 0 (true for all shapes here).
// ---------------------------------------------------------------------------
template <int BIAS, int RELU>
__global__ __launch_bounds__(256) void gemm64(const float* __restrict__ A,
                                              const float* __restrict__ B,
                                              const float* __restrict__ bias,
                                              float* __restrict__ C,
                                              int M, int N, int Kdim) {
    __shared__ float As[16][65];  // [k][m], padded (reads are broadcast, writes <=4-way)
    __shared__ float Bs[16][64];  // [k][n], unpadded (aligned float4 store, 2-way reads = free)

    const int t  = threadIdx.x;
    const int bm = blockIdx.y * 64;
    const int bn = blockIdx.x * 64;
    const int ty = t >> 4;        // 0..15 -> rows ty*4..+4
    const int tx = t & 15;        // 0..15 -> cols tx*4..+4

    // cooperative-load indices
    const int lar = t >> 2;           // 0..63 : A-tile row
    const int lak = (t & 3) * 4;      // k offset (float4)
    const int lbr = t >> 4;           // 0..15 : B-tile k-row
    const int lbc = (t & 15) * 4;     // col offset (float4)

    float acc[4][4] = {};

    for (int k0 = 0; k0 < Kdim; k0 += 16) {
        float4 av = *reinterpret_cast<const float4*>(&A[(size_t)(bm + lar) * Kdim + k0 + lak]);
        float4 bv = *reinterpret_cast<const float4*>(&B[(size_t)(k0 + lbr) * N + bn + lbc]);
        As[lak + 0][lar] = av.x;
        As[lak + 1][lar] = av.y;
        As[lak + 2][lar] = av.z;
        As[lak + 3][lar] = av.w;
        *reinterpret_cast<float4*>(&Bs[lbr][lbc]) = bv;
        __syncthreads();
#pragma unroll
        for (int k = 0; k < 16; ++k) {
            float a[4], b[4];
#pragma unroll
            for (int i = 0; i < 4; ++i) a[i] = As[k][ty * 4 + i];
#pragma unroll
            for (int j = 0; j < 4; ++j) b[j] = Bs[k][tx * 4 + j];
#pragma unroll
            for (int i = 0; i < 4; ++i)
#pragma unroll
                for (int j = 0; j < 4; ++j) acc[i][j] += a[i] * b[j];
        }
        __syncthreads();
    }

    // epilogue
#pragma unroll
    for (int i = 0; i < 4; ++i) {
        float4 o;
        float* pr = &acc[i][0];
        if (BIAS) {
#pragma unroll
            for (int j = 0; j < 4; ++j) pr[j] += bias[bn + tx * 4 + j];
        }
        if (RELU) {
#pragma unroll
            for (int j = 0; j < 4; ++j) pr[j] = fmaxf(pr[j], 0.0f);
        }
        o.x = pr[0]; o.y = pr[1]; o.z = pr[2]; o.w = pr[3];
        *reinterpret_cast<float4*>(&C[(size_t)(bm + ty * 4 + i) * N + bn + tx * 4]) = o;
    }
}

// ---------------------------------------------------------------------------
// Flash-style attention, fp32.
// Q,K,V layout: (B, L, NHEADS*HDIM), col = h*64 + d.
// Each block: one (b, h, 64-row Q tile). 256 threads, 4x4 micro-tiles.
// Output written directly in (B, L, NHEADS*HDIM) "heads" layout.
// ---------------------------------------------------------------------------
__global__ __launch_bounds__(256) void attn64(const float* __restrict__ Q,
                                              const float* __restrict__ K,
                                              const float* __restrict__ V,
                                              float* __restrict__ O) {
    __shared__ float Qs[64][65];
    __shared__ float Ks[64][65];
    __shared__ float Vs[64][65];
    __shared__ float Ps[64][65];

    const int t  = threadIdx.x;
    const int q0 = blockIdx.x * 64;
    const int h  = blockIdx.y;
    const int b  = blockIdx.z;
    const size_t base = (size_t)b * SEQ * (NHEADS * HDIM) + (size_t)h * HDIM;
    const int C = NHEADS * HDIM;  // 512 row stride

    // ---- load Q tile (pre-scaled by 1/sqrt(Dh)) ----
    const int lr = t >> 4;           // 0..15
    const int lc = (t & 15) * 4;     // 0..60
    const float scale = 0.125f;      // 1/sqrt(64)
#pragma unroll
    for (int rr = 0; rr < 4; ++rr) {
        int row = rr * 16 + lr;
        float4 v4 = *reinterpret_cast<const float4*>(&Q[base + (size_t)(q0 + row) * C + lc]);
        Qs[row][lc + 0] = v4.x * scale;
        Qs[row][lc + 1] = v4.y * scale;
        Qs[row][lc + 2] = v4.z * scale;
        Qs[row][lc + 3] = v4.w * scale;
    }

    const int r0 = (t >> 4) * 4;     // 4 rows r0..r0+3
    const int c0 = (t & 15) * 4;     // 4 cols c0..c0+3

    float m[4], l[4];
    float o[4][4] = {};
#pragma unroll
    for (int i = 0; i < 4; ++i) { m[i] = -1e30f; l[i] = 0.0f; }

    for (int kt = 0; kt < SEQ; kt += 64) {
        __syncthreads();  // previous tile fully consumed (also covers Qs on first iter)
        // ---- load K,V tiles ----
#pragma unroll
        for (int rr = 0; rr < 4; ++rr) {
            int row = rr * 16 + lr;
            float4 kv = *reinterpret_cast<const float4*>(&K[base + (size_t)(kt + row) * C + lc]);
            float4 vv = *reinterpret_cast<const float4*>(&V[base + (size_t)(kt + row) * C + lc]);
            Ks[row][lc + 0] = kv.x; Ks[row][lc + 1] = kv.y;
            Ks[row][lc + 2] = kv.z; Ks[row][lc + 3] = kv.w;
            Vs[row][lc + 0] = vv.x; Vs[row][lc + 1] = vv.y;
            Vs[row][lc + 2] = vv.z; Vs[row][lc + 3] = vv.w;
        }
        __syncthreads();

        // ---- S = Q K^T (4x4 per thread) ----
        float s[4][4] = {};
#pragma unroll 16
        for (int d = 0; d < 64; ++d) {
            float a[4], bk[4];
#pragma unroll
            for (int i = 0; i < 4; ++i) a[i]  = Qs[r0 + i][d];
#pragma unroll
            for (int j = 0; j < 4; ++j) bk[j] = Ks[c0 + j][d];
#pragma unroll
            for (int i = 0; i < 4; ++i)
#pragma unroll
                for (int j = 0; j < 4; ++j) s[i][j] += a[i] * bk[j];
        }

        // ---- online softmax update (row groups = 16 lanes: tx 0..15) ----
#pragma unroll
        for (int i = 0; i < 4; ++i) {
            float tm = fmaxf(fmaxf(s[i][0], s[i][1]), fmaxf(s[i][2], s[i][3]));
            tm = fmaxf(tm, __shfl_xor(tm, 1));
            tm = fmaxf(tm, __shfl_xor(tm, 2));
            tm = fmaxf(tm, __shfl_xor(tm, 4));
            tm = fmaxf(tm, __shfl_xor(tm, 8));
            float mn = fmaxf(m[i], tm);
            float rescale = __expf(m[i] - mn);
            m[i] = mn;
            float psum = 0.0f;
#pragma unroll
            for (int j = 0; j < 4; ++j) {
                float pv = __expf(s[i][j] - mn);
                Ps[r0 + i][c0 + j] = pv;
                psum += pv;
            }
            psum += __shfl_xor(psum, 1);
            psum += __shfl_xor(psum, 2);
            psum += __shfl_xor(psum, 4);
            psum += __shfl_xor(psum, 8);
            l[i] = l[i] * rescale + psum;
#pragma unroll
            for (int j = 0; j < 4; ++j) o[i][j] *= rescale;
        }
        __syncthreads();  // Ps visible to all

        // ---- O += P @ V ----
#pragma unroll 16
        for (int k = 0; k < 64; ++k) {
            float p[4], vv[4];
#pragma unroll
            for (int i = 0; i < 4; ++i) p[i]  = Ps[r0 + i][k];
#pragma unroll
            for (int j = 0; j < 4; ++j) vv[j] = Vs[k][c0 + j];
#pragma unroll
            for (int i = 0; i < 4; ++i)
#pragma unroll
                for (int j = 0; j < 4; ++j) o[i][j] += p[i] * vv[j];
        }
    }

    // ---- finalize + store in (B, L, H*D) layout ----
#pragma unroll
    for (int i = 0; i < 4; ++i) {
        float inv = 1.0f / l[i];
        float4 ov;
        ov.x = o[i][0] * inv; ov.y = o[i][1] * inv;
        ov.z = o[i][2] * inv; ov.w = o[i][3] * inv;
        *reinterpret_cast<float4*>(&O[base + (size_t)(q0 + r0 + i) * C + c0]) = ov;
    }
}

// ---------------------------------------------------------------------------
extern "C" void kernel_launch(void* const* d_in, const int* in_sizes, int n_in,
                              void* d_out, int out_size, void* d_ws, size_t ws_size,
                              hipStream_t stream) {
    const float* x  = (const float*)d_in[0];   // (B, L, EMBED)
    const float* pW = (const float*)d_in[1];   // (EMBED, PROJ)
    const float* pb = (const float*)d_in[2];   // (PROJ)
    const float* Wq = (const float*)d_in[3];   // (PROJ, H, Dh) == (PROJ, PROJ) flat
    const float* Wk = (const float*)d_in[4];
    const float* Wv = (const float*)d_in[5];
    const float* oW = (const float*)d_in[6];   // (PROJ, EMBED)
    float* out = (float*)d_out;

    float* p  = (float*)d_ws;                       // (BL, PROJ)
    float* q  = p + (size_t)BL * PROJ;              // (B, L, H*Dh)
    float* k  = q + (size_t)BL * PROJ;
    float* v  = k + (size_t)BL * PROJ;
    float* hd = v + (size_t)BL * PROJ;              // heads, (B, L, H*Dh)

    dim3 blk(256);

    // p = relu(x @ proj_W + b)
    gemm64<1, 1><<<dim3(PROJ / 64, BL / 64), blk, 0, stream>>>(x, pW, pb, p, BL, PROJ, EMBED);
    // q/k/v = p @ W*  (weight (C,H,Dh) flattens to (C, H*Dh))
    gemm64<0, 0><<<dim3(PROJ / 64, BL / 64), blk, 0, stream>>>(p, Wq, nullptr, q, BL, PROJ, PROJ);
    gemm64<0, 0><<<dim3(PROJ / 64, BL / 64), blk, 0, stream>>>(p, Wk, nullptr, k, BL, PROJ, PROJ);
    gemm64<0, 0><<<dim3(PROJ / 64, BL / 64), blk, 0, stream>>>(p, Wv, nullptr, v, BL, PROJ, PROJ);
    // attention (flash-style, writes heads in (B,L,H*Dh))
    attn64<<<dim3(SEQ / 64, NHEADS, BATCH), blk, 0, stream>>>(q, k, v, hd);
    // out = heads @ out_W
    gemm64<0, 0><<<dim3(EMBED / 64, BL / 64), blk, 0, stream>>>(hd, oW, nullptr, out, BL, EMBED, PROJ);
}

// Round 3
// 319.548 us; speedup vs baseline: 1.9764x; 1.9764x over previous
//
#include <hip/hip_runtime.h>
#include <math.h>

#define BATCH 2
#define SEQ 2048
#define BL (BATCH * SEQ)      // 4096
#define EMBED 1024
#define PROJ 512
#define NHEADS 8
#define HDIM 64

typedef _Float16 half8 __attribute__((ext_vector_type(8)));
typedef float floatx4 __attribute__((ext_vector_type(4)));

// ---------------------------------------------------------------------------
// Tiled fp32 GEMM: C[M][N] = op(A[M][K] @ B[K][N] (+ bias))  (unchanged)
// ---------------------------------------------------------------------------
template <int BIAS, int RELU>
__global__ __launch_bounds__(256) void gemm64(const float* __restrict__ A,
                                              const float* __restrict__ B,
                                              const float* __restrict__ bias,
                                              float* __restrict__ C,
                                              int M, int N, int Kdim) {
    __shared__ float As[16][65];
    __shared__ float Bs[16][64];

    const int t  = threadIdx.x;
    const int bm = blockIdx.y * 64;
    const int bn = blockIdx.x * 64;
    const int ty = t >> 4;
    const int tx = t & 15;

    const int lar = t >> 2;
    const int lak = (t & 3) * 4;
    const int lbr = t >> 4;
    const int lbc = (t & 15) * 4;

    float acc[4][4] = {};

    for (int k0 = 0; k0 < Kdim; k0 += 16) {
        float4 av = *reinterpret_cast<const float4*>(&A[(size_t)(bm + lar) * Kdim + k0 + lak]);
        float4 bv = *reinterpret_cast<const float4*>(&B[(size_t)(k0 + lbr) * N + bn + lbc]);
        As[lak + 0][lar] = av.x;
        As[lak + 1][lar] = av.y;
        As[lak + 2][lar] = av.z;
        As[lak + 3][lar] = av.w;
        *reinterpret_cast<float4*>(&Bs[lbr][lbc]) = bv;
        __syncthreads();
#pragma unroll
        for (int k = 0; k < 16; ++k) {
            float a[4], b[4];
#pragma unroll
            for (int i = 0; i < 4; ++i) a[i] = As[k][ty * 4 + i];
#pragma unroll
            for (int j = 0; j < 4; ++j) b[j] = Bs[k][tx * 4 + j];
#pragma unroll
            for (int i = 0; i < 4; ++i)
#pragma unroll
                for (int j = 0; j < 4; ++j) acc[i][j] += a[i] * b[j];
        }
        __syncthreads();
    }

#pragma unroll
    for (int i = 0; i < 4; ++i) {
        float4 o;
        float* pr = &acc[i][0];
        if (BIAS) {
#pragma unroll
            for (int j = 0; j < 4; ++j) pr[j] += bias[bn + tx * 4 + j];
        }
        if (RELU) {
#pragma unroll
            for (int j = 0; j < 4; ++j) pr[j] = fmaxf(pr[j], 0.0f);
        }
        o.x = pr[0]; o.y = pr[1]; o.z = pr[2]; o.w = pr[3];
        *reinterpret_cast<float4*>(&C[(size_t)(bm + ty * 4 + i) * N + bn + tx * 4]) = o;
    }
}

// ---------------------------------------------------------------------------
// f16-MFMA flash attention.
// Q,K,V fp32 in (B, L, 512) layout, col = h*64 + d. O fp32 same layout.
// Block: (b, h, 128 q rows). 4 waves x 32 q rows. KV tile = 64.
// Swapped QK^T: S^T = (K @ Q^T) so softmax reduction is 16 local + 2 shfl.
// Layout facts used (verified in docs):
//   A-frag: row = lane&15 (+16*mf), k = (lane>>4)*8 + i   [same map for B cols]
//   C/D   : col = lane&15, row = (lane>>4)*4 + reg
// ---------------------------------------------------------------------------
__global__ __launch_bounds__(256) void attn_mfma(const float* __restrict__ Q,
                                                 const float* __restrict__ K,
                                                 const float* __restrict__ V,
                                                 float* __restrict__ O) {
    __shared__ _Float16 Ks[64][72];       // [kv][d]    144B rows, 16B aligned
    __shared__ _Float16 Vt[64][72];       // [d][kv]    transposed V
    __shared__ _Float16 Ps[4][32][72];    // per-wave P: [q_local][kv]

    const int t  = threadIdx.x;
    const int w  = t >> 6;        // wave 0..3
    const int l  = t & 63;
    const int lr = l & 15;
    const int lg = l >> 4;        // 0..3

    const int q0 = blockIdx.x * 128;
    const int h  = blockIdx.y;
    const int b  = blockIdx.z;
    const size_t base = (size_t)b * SEQ * PROJ + (size_t)h * HDIM;

    // ---- Q fragments in registers (B-operand layout), scale 1/8 folded ----
    half8 qf[2][2];  // [nf(q 16-block)][s(d 32-block)]
#pragma unroll
    for (int nf = 0; nf < 2; ++nf)
#pragma unroll
        for (int s = 0; s < 2; ++s) {
            const int qrow = q0 + w * 32 + nf * 16 + lr;
            const float* qp = Q + base + (size_t)qrow * PROJ + s * 32 + lg * 8;
            float4 a = *reinterpret_cast<const float4*>(qp);
            float4 c = *reinterpret_cast<const float4*>(qp + 4);
            half8 q8;
            q8[0] = (_Float16)(a.x * 0.125f); q8[1] = (_Float16)(a.y * 0.125f);
            q8[2] = (_Float16)(a.z * 0.125f); q8[3] = (_Float16)(a.w * 0.125f);
            q8[4] = (_Float16)(c.x * 0.125f); q8[5] = (_Float16)(c.y * 0.125f);
            q8[6] = (_Float16)(c.z * 0.125f); q8[7] = (_Float16)(c.w * 0.125f);
            qf[nf][s] = q8;
        }

    floatx4 o_acc[2][4];  // [mf_o(q 16-block)][nf_d(d 16-block)]
#pragma unroll
    for (int i = 0; i < 2; ++i)
#pragma unroll
        for (int j = 0; j < 4; ++j) o_acc[i][j] = (floatx4){0.f, 0.f, 0.f, 0.f};

    float m_s[2] = {-1e30f, -1e30f};
    float l_s[2] = {0.f, 0.f};

    // staging assignment: thread t covers K/V row (t>>2), 16 d's at (t&3)*16
    const int rkv = t >> 2;
    const int d0  = (t & 3) * 16;

    for (int kt = 0; kt < SEQ; kt += 64) {
        __syncthreads();  // prior tile's LDS reads complete

        // ---- stage K (row-major) and V (transposed) as f16 ----
        {
            const float* kp = K + base + (size_t)(kt + rkv) * PROJ + d0;
            const float* vp = V + base + (size_t)(kt + rkv) * PROJ + d0;
            _Float16 kh[16], vh[16];
#pragma unroll
            for (int i = 0; i < 16; i += 4) {
                float4 k4 = *reinterpret_cast<const float4*>(kp + i);
                float4 v4 = *reinterpret_cast<const float4*>(vp + i);
                kh[i + 0] = (_Float16)k4.x; kh[i + 1] = (_Float16)k4.y;
                kh[i + 2] = (_Float16)k4.z; kh[i + 3] = (_Float16)k4.w;
                vh[i + 0] = (_Float16)v4.x; vh[i + 1] = (_Float16)v4.y;
                vh[i + 2] = (_Float16)v4.z; vh[i + 3] = (_Float16)v4.w;
            }
            half8 k8a, k8b;
#pragma unroll
            for (int i = 0; i < 8; ++i) { k8a[i] = kh[i]; k8b[i] = kh[8 + i]; }
            *reinterpret_cast<half8*>(&Ks[rkv][d0])     = k8a;
            *reinterpret_cast<half8*>(&Ks[rkv][d0 + 8]) = k8b;
#pragma unroll
            for (int i = 0; i < 16; ++i) Vt[d0 + i][rkv] = vh[i];
        }
        __syncthreads();  // staging visible

        // ---- S^T = K @ Q^T : D frags [mf(kv 16-blk)][nf(q 16-blk)] ----
        floatx4 st[4][2];
#pragma unroll
        for (int i = 0; i < 4; ++i)
#pragma unroll
            for (int j = 0; j < 2; ++j) st[i][j] = (floatx4){0.f, 0.f, 0.f, 0.f};
#pragma unroll
        for (int s = 0; s < 2; ++s)
#pragma unroll
            for (int mf = 0; mf < 4; ++mf) {
                half8 ka = *reinterpret_cast<const half8*>(&Ks[mf * 16 + lr][s * 32 + lg * 8]);
                st[mf][0] = __builtin_amdgcn_mfma_f32_16x16x32_f16(ka, qf[0][s], st[mf][0], 0, 0, 0);
                st[mf][1] = __builtin_amdgcn_mfma_f32_16x16x32_f16(ka, qf[1][s], st[mf][1], 0, 0, 0);
            }

        // ---- online softmax: lane owns full kv-column for q = nf*16+lr ----
        float fscale[2];
#pragma unroll
        for (int nf = 0; nf < 2; ++nf) {
            float tm = -1e30f;
#pragma unroll
            for (int mf = 0; mf < 4; ++mf)
#pragma unroll
                for (int r = 0; r < 4; ++r) tm = fmaxf(tm, st[mf][nf][r]);
            tm = fmaxf(tm, __shfl_xor(tm, 16));
            tm = fmaxf(tm, __shfl_xor(tm, 32));
            float mn = fmaxf(m_s[nf], tm);
            fscale[nf] = __expf(m_s[nf] - mn);
            m_s[nf] = mn;
            float sum = 0.f;
#pragma unroll
            for (int mf = 0; mf < 4; ++mf)
#pragma unroll
                for (int r = 0; r < 4; ++r) {
                    float p = __expf(st[mf][nf][r] - mn);
                    st[mf][nf][r] = p;
                    sum += p;
                }
            sum += __shfl_xor(sum, 16);
            sum += __shfl_xor(sum, 32);
            l_s[nf] = l_s[nf] * fscale[nf] + sum;
        }

        // ---- write P (f16) to wave-private LDS in PV A-layout: Ps[q][kv] ----
#pragma unroll
        for (int nf = 0; nf < 2; ++nf)
#pragma unroll
            for (int mf = 0; mf < 4; ++mf)
#pragma unroll
                for (int rp = 0; rp < 2; ++rp) {
                    union { _Float16 hh[2]; unsigned int u; } pk;
                    pk.hh[0] = (_Float16)st[mf][nf][2 * rp];
                    pk.hh[1] = (_Float16)st[mf][nf][2 * rp + 1];
                    *reinterpret_cast<unsigned int*>(
                        &Ps[w][nf * 16 + lr][mf * 16 + lg * 4 + rp * 2]) = pk.u;
                }
        __syncthreads();  // cross-lane P visibility (conservative)

        // ---- rescale O by exp(m_old - m_new), per row ----
#pragma unroll
        for (int mf_o = 0; mf_o < 2; ++mf_o)
#pragma unroll
            for (int r = 0; r < 4; ++r) {
                float f = __shfl(fscale[mf_o], lg * 4 + r);
#pragma unroll
                for (int nf_d = 0; nf_d < 4; ++nf_d) o_acc[mf_o][nf_d][r] *= f;
            }

        // ---- O += P @ V ----
#pragma unroll
        for (int s = 0; s < 2; ++s) {
            half8 pa0 = *reinterpret_cast<const half8*>(&Ps[w][0 * 16 + lr][s * 32 + lg * 8]);
            half8 pa1 = *reinterpret_cast<const half8*>(&Ps[w][1 * 16 + lr][s * 32 + lg * 8]);
#pragma unroll
            for (int nf_d = 0; nf_d < 4; ++nf_d) {
                half8 vb = *reinterpret_cast<const half8*>(&Vt[nf_d * 16 + lr][s * 32 + lg * 8]);
                o_acc[0][nf_d] = __builtin_amdgcn_mfma_f32_16x16x32_f16(pa0, vb, o_acc[0][nf_d], 0, 0, 0);
                o_acc[1][nf_d] = __builtin_amdgcn_mfma_f32_16x16x32_f16(pa1, vb, o_acc[1][nf_d], 0, 0, 0);
            }
        }
    }

    // ---- finalize: divide by l, store fp32 heads layout ----
#pragma unroll
    for (int mf_o = 0; mf_o < 2; ++mf_o)
#pragma unroll
        for (int r = 0; r < 4; ++r) {
            float inv = 1.0f / __shfl(l_s[mf_o], lg * 4 + r);
            const int qrow = q0 + w * 32 + mf_o * 16 + lg * 4 + r;
#pragma unroll
            for (int nf_d = 0; nf_d < 4; ++nf_d)
                O[base + (size_t)qrow * PROJ + nf_d * 16 + lr] = o_acc[mf_o][nf_d][r] * inv;
        }
}

// ---------------------------------------------------------------------------
extern "C" void kernel_launch(void* const* d_in, const int* in_sizes, int n_in,
                              void* d_out, int out_size, void* d_ws, size_t ws_size,
                              hipStream_t stream) {
    const float* x  = (const float*)d_in[0];   // (B, L, EMBED)
    const float* pW = (const float*)d_in[1];   // (EMBED, PROJ)
    const float* pb = (const float*)d_in[2];   // (PROJ)
    const float* Wq = (const float*)d_in[3];   // (PROJ, H*Dh)
    const float* Wk = (const float*)d_in[4];
    const float* Wv = (const float*)d_in[5];
    const float* oW = (const float*)d_in[6];   // (PROJ, EMBED)
    float* out = (float*)d_out;

    float* p  = (float*)d_ws;
    float* q  = p + (size_t)BL * PROJ;
    float* k  = q + (size_t)BL * PROJ;
    float* v  = k + (size_t)BL * PROJ;
    float* hd = v + (size_t)BL * PROJ;

    dim3 blk(256);

    gemm64<1, 1><<<dim3(PROJ / 64, BL / 64), blk, 0, stream>>>(x, pW, pb, p, BL, PROJ, EMBED);
    gemm64<0, 0><<<dim3(PROJ / 64, BL / 64), blk, 0, stream>>>(p, Wq, nullptr, q, BL, PROJ, PROJ);
    gemm64<0, 0><<<dim3(PROJ / 64, BL / 64), blk, 0, stream>>>(p, Wk, nullptr, k, BL, PROJ, PROJ);
    gemm64<0, 0><<<dim3(PROJ / 64, BL / 64), blk, 0, stream>>>(p, Wv, nullptr, v, BL, PROJ, PROJ);

    attn_mfma<<<dim3(SEQ / 128, NHEADS, BATCH), blk, 0, stream>>>(q, k, v, hd);

    gemm64<0, 0><<<dim3(EMBED / 64, BL / 64), blk, 0, stream>>>(hd, oW, nullptr, out, BL, EMBED, PROJ);
}

// Round 4
// 137.032 us; speedup vs baseline: 4.6088x; 2.3319x over previous
//
#include <hip/hip_runtime.h>
#include <math.h>

#define BATCH 2
#define SEQ 2048
#define BL (BATCH * SEQ)      // 4096
#define EMBED 1024
#define PROJ 512
#define NHEADS 8
#define HDIM 64
#define QKVN (3 * PROJ)       // 1536 fused q|k|v columns

typedef _Float16 half8 __attribute__((ext_vector_type(8)));
typedef float floatx4 __attribute__((ext_vector_type(4)));

// ---------------------------------------------------------------------------
// Weight prep: dst[n][k] = (f16)(src[k][n] * scale)   (transpose + convert)
// 64x64 tiles via LDS. K,N multiples of 64.
// ---------------------------------------------------------------------------
__global__ __launch_bounds__(256) void trconv(const float* __restrict__ src,
                                              _Float16* __restrict__ dst,
                                              int K, int N, float scale) {
    __shared__ float tile[64][65];
    const int t  = threadIdx.x;
    const int n0 = blockIdx.x * 64;
    const int k0 = blockIdx.y * 64;
    const int tx = t & 63;
    const int ty = t >> 6;   // 0..3
#pragma unroll
    for (int i = 0; i < 16; ++i) {
        int k = ty * 16 + i;
        tile[k][tx] = src[(size_t)(k0 + k) * N + n0 + tx];
    }
    __syncthreads();
#pragma unroll
    for (int i = 0; i < 16; ++i) {
        int n = ty * 16 + i;
        dst[(size_t)(n0 + n) * K + k0 + tx] = (_Float16)(tile[tx][n] * scale);
    }
}

// ---------------------------------------------------------------------------
// f16 MFMA GEMM: C[M][N] = A[M][K] @ Bt[N][K]^T (+bias, relu), fp32 accum.
// A: fp32 (converted during staging) if A_F32 else f16.
// C: fp32 if C_F32 else f16.
// Block tile 64(M) x 128(N), BK=32, 256 threads = 4 waves (2x2 of 32x64).
// LDS rows padded to 40 f16 (80 B) -> frag reads spread across 8 bank slots.
// Reg-prefetch of next K-tile overlaps global latency with MFMA phase.
// ---------------------------------------------------------------------------
template <int A_F32, int BIASRELU, int C_F32>
__global__ __launch_bounds__(256) void gemm_mfma(const void* __restrict__ Ap,
                                                 const _Float16* __restrict__ Bt,
                                                 const float* __restrict__ bias,
                                                 void* __restrict__ Cp,
                                                 int M, int N, int K) {
    __shared__ _Float16 Ah[64][40];
    __shared__ _Float16 Bh[128][40];

    const int t  = threadIdx.x;
    const int w  = t >> 6;
    const int l  = t & 63;
    const int lr = l & 15;
    const int lg = l >> 4;
    const int bm = blockIdx.y * 64;
    const int bn = blockIdx.x * 128;
    const int wr = w >> 1;       // wave row 0..1 -> m offset wr*32
    const int wc = w & 1;        // wave col 0..1 -> n offset wc*64

    // staging assignments
    const int ar = t >> 2, ac = (t & 3) * 8;    // A: 64 rows x 32 k, 8 f16/thread
    const int br = t >> 1, bc = (t & 1) * 16;   // B: 128 rows x 32 k, 16 f16/thread

    floatx4 acc[2][4];
#pragma unroll
    for (int i = 0; i < 2; ++i)
#pragma unroll
        for (int j = 0; j < 4; ++j) acc[i][j] = (floatx4){0.f, 0.f, 0.f, 0.f};

    // prefetch registers
    float4 af0, af1;
    half8 areg, breg0, breg1;

    const float* Af = (const float*)Ap;
    const _Float16* Ah16 = (const _Float16*)Ap;

    // initial loads (tile 0)
    if (A_F32) {
        af0 = *reinterpret_cast<const float4*>(&Af[(size_t)(bm + ar) * K + ac]);
        af1 = *reinterpret_cast<const float4*>(&Af[(size_t)(bm + ar) * K + ac + 4]);
    } else {
        areg = *reinterpret_cast<const half8*>(&Ah16[(size_t)(bm + ar) * K + ac]);
    }
    breg0 = *reinterpret_cast<const half8*>(&Bt[(size_t)(bn + br) * K + bc]);
    breg1 = *reinterpret_cast<const half8*>(&Bt[(size_t)(bn + br) * K + bc + 8]);

    for (int kt = 0; kt < K; kt += 32) {
        // ---- write staged regs to LDS ----
        if (A_F32) {
            half8 h;
            h[0] = (_Float16)af0.x; h[1] = (_Float16)af0.y;
            h[2] = (_Float16)af0.z; h[3] = (_Float16)af0.w;
            h[4] = (_Float16)af1.x; h[5] = (_Float16)af1.y;
            h[6] = (_Float16)af1.z; h[7] = (_Float16)af1.w;
            *reinterpret_cast<half8*>(&Ah[ar][ac]) = h;
        } else {
            *reinterpret_cast<half8*>(&Ah[ar][ac]) = areg;
        }
        *reinterpret_cast<half8*>(&Bh[br][bc])     = breg0;
        *reinterpret_cast<half8*>(&Bh[br][bc + 8]) = breg1;
        __syncthreads();

        // ---- prefetch next tile while MFMAs run ----
        if (kt + 32 < K) {
            if (A_F32) {
                af0 = *reinterpret_cast<const float4*>(&Af[(size_t)(bm + ar) * K + kt + 32 + ac]);
                af1 = *reinterpret_cast<const float4*>(&Af[(size_t)(bm + ar) * K + kt + 32 + ac + 4]);
            } else {
                areg = *reinterpret_cast<const half8*>(&Ah16[(size_t)(bm + ar) * K + kt + 32 + ac]);
            }
            breg0 = *reinterpret_cast<const half8*>(&Bt[(size_t)(bn + br) * K + kt + 32 + bc]);
            breg1 = *reinterpret_cast<const half8*>(&Bt[(size_t)(bn + br) * K + kt + 32 + bc + 8]);
        }

        // ---- fragments + MFMA ----
        half8 afr[2], bfr[4];
#pragma unroll
        for (int mf = 0; mf < 2; ++mf)
            afr[mf] = *reinterpret_cast<const half8*>(&Ah[wr * 32 + mf * 16 + lr][lg * 8]);
#pragma unroll
        for (int nf = 0; nf < 4; ++nf)
            bfr[nf] = *reinterpret_cast<const half8*>(&Bh[wc * 64 + nf * 16 + lr][lg * 8]);
#pragma unroll
        for (int mf = 0; mf < 2; ++mf)
#pragma unroll
            for (int nf = 0; nf < 4; ++nf)
                acc[mf][nf] = __builtin_amdgcn_mfma_f32_16x16x32_f16(afr[mf], bfr[nf], acc[mf][nf], 0, 0, 0);

        __syncthreads();
    }

    // ---- epilogue ----
#pragma unroll
    for (int mf = 0; mf < 2; ++mf)
#pragma unroll
        for (int nf = 0; nf < 4; ++nf) {
            const int n = bn + wc * 64 + nf * 16 + lr;
            float bs = 0.f;
            if (BIASRELU) bs = bias[n];
#pragma unroll
            for (int r = 0; r < 4; ++r) {
                const int m = bm + wr * 32 + mf * 16 + lg * 4 + r;
                float v = acc[mf][nf][r];
                if (BIASRELU) v = fmaxf(v + bs, 0.f);
                if (C_F32)
                    ((float*)Cp)[(size_t)m * N + n] = v;
                else
                    ((_Float16*)Cp)[(size_t)m * N + n] = (_Float16)v;
            }
        }
}

// ---------------------------------------------------------------------------
// f16-MFMA flash attention. Q,K,V f16, row stride QKVN (fused qkv buffer),
// col = h*64 + d (+0/+512/+1024 folded into the passed pointers).
// O f16, row stride PROJ. Softmax scale pre-folded into Wq.
// Block: (b, h, 128 q rows). 4 waves x 32 q rows. KV tile = 64.
// ---------------------------------------------------------------------------
__global__ __launch_bounds__(256) void attn_mfma(const _Float16* __restrict__ Q,
                                                 const _Float16* __restrict__ K,
                                                 const _Float16* __restrict__ V,
                                                 _Float16* __restrict__ O) {
    __shared__ _Float16 Ks[64][72];       // [kv][d]
    __shared__ _Float16 Vt[64][72];       // [d][kv]
    __shared__ _Float16 Ps[4][32][72];    // per-wave P: [q_local][kv]

    const int t  = threadIdx.x;
    const int w  = t >> 6;
    const int l  = t & 63;
    const int lr = l & 15;
    const int lg = l >> 4;

    const int q0 = blockIdx.x * 128;
    const int h  = blockIdx.y;
    const int b  = blockIdx.z;
    const size_t base  = (size_t)b * SEQ * QKVN + (size_t)h * HDIM;  // q/k/v
    const size_t baseO = (size_t)b * SEQ * PROJ + (size_t)h * HDIM;  // output

    // ---- Q fragments (B-operand layout) ----
    half8 qf[2][2];
#pragma unroll
    for (int nf = 0; nf < 2; ++nf)
#pragma unroll
        for (int s = 0; s < 2; ++s) {
            const int qrow = q0 + w * 32 + nf * 16 + lr;
            qf[nf][s] = *reinterpret_cast<const half8*>(
                &Q[base + (size_t)qrow * QKVN + s * 32 + lg * 8]);
        }

    floatx4 o_acc[2][4];
#pragma unroll
    for (int i = 0; i < 2; ++i)
#pragma unroll
        for (int j = 0; j < 4; ++j) o_acc[i][j] = (floatx4){0.f, 0.f, 0.f, 0.f};

    float m_s[2] = {-1e30f, -1e30f};
    float l_s[2] = {0.f, 0.f};

    const int rkv = t >> 2;
    const int d0  = (t & 3) * 16;

    for (int kt = 0; kt < SEQ; kt += 64) {
        __syncthreads();

        // ---- stage K (row-major) and V (transposed) ----
        {
            const _Float16* kp = K + base + (size_t)(kt + rkv) * QKVN + d0;
            const _Float16* vp = V + base + (size_t)(kt + rkv) * QKVN + d0;
            half8 k8a = *reinterpret_cast<const half8*>(kp);
            half8 k8b = *reinterpret_cast<const half8*>(kp + 8);
            half8 v8a = *reinterpret_cast<const half8*>(vp);
            half8 v8b = *reinterpret_cast<const half8*>(vp + 8);
            *reinterpret_cast<half8*>(&Ks[rkv][d0])     = k8a;
            *reinterpret_cast<half8*>(&Ks[rkv][d0 + 8]) = k8b;
#pragma unroll
            for (int i = 0; i < 8; ++i) {
                Vt[d0 + i][rkv]     = v8a[i];
                Vt[d0 + 8 + i][rkv] = v8b[i];
            }
        }
        __syncthreads();

        // ---- S^T = K @ Q^T ----
        floatx4 st[4][2];
#pragma unroll
        for (int i = 0; i < 4; ++i)
#pragma unroll
            for (int j = 0; j < 2; ++j) st[i][j] = (floatx4){0.f, 0.f, 0.f, 0.f};
#pragma unroll
        for (int s = 0; s < 2; ++s)
#pragma unroll
            for (int mf = 0; mf < 4; ++mf) {
                half8 ka = *reinterpret_cast<const half8*>(&Ks[mf * 16 + lr][s * 32 + lg * 8]);
                st[mf][0] = __builtin_amdgcn_mfma_f32_16x16x32_f16(ka, qf[0][s], st[mf][0], 0, 0, 0);
                st[mf][1] = __builtin_amdgcn_mfma_f32_16x16x32_f16(ka, qf[1][s], st[mf][1], 0, 0, 0);
            }

        // ---- online softmax ----
        float fscale[2];
#pragma unroll
        for (int nf = 0; nf < 2; ++nf) {
            float tm = -1e30f;
#pragma unroll
            for (int mf = 0; mf < 4; ++mf)
#pragma unroll
                for (int r = 0; r < 4; ++r) tm = fmaxf(tm, st[mf][nf][r]);
            tm = fmaxf(tm, __shfl_xor(tm, 16));
            tm = fmaxf(tm, __shfl_xor(tm, 32));
            float mn = fmaxf(m_s[nf], tm);
            fscale[nf] = __expf(m_s[nf] - mn);
            m_s[nf] = mn;
            float sum = 0.f;
#pragma unroll
            for (int mf = 0; mf < 4; ++mf)
#pragma unroll
                for (int r = 0; r < 4; ++r) {
                    float p = __expf(st[mf][nf][r] - mn);
                    st[mf][nf][r] = p;
                    sum += p;
                }
            sum += __shfl_xor(sum, 16);
            sum += __shfl_xor(sum, 32);
            l_s[nf] = l_s[nf] * fscale[nf] + sum;
        }

        // ---- P -> wave-private LDS (PV A-layout) ----
#pragma unroll
        for (int nf = 0; nf < 2; ++nf)
#pragma unroll
            for (int mf = 0; mf < 4; ++mf)
#pragma unroll
                for (int rp = 0; rp < 2; ++rp) {
                    union { _Float16 hh[2]; unsigned int u; } pk;
                    pk.hh[0] = (_Float16)st[mf][nf][2 * rp];
                    pk.hh[1] = (_Float16)st[mf][nf][2 * rp + 1];
                    *reinterpret_cast<unsigned int*>(
                        &Ps[w][nf * 16 + lr][mf * 16 + lg * 4 + rp * 2]) = pk.u;
                }
        __syncthreads();

        // ---- rescale O ----
#pragma unroll
        for (int mf_o = 0; mf_o < 2; ++mf_o)
#pragma unroll
            for (int r = 0; r < 4; ++r) {
                float f = __shfl(fscale[mf_o], lg * 4 + r);
#pragma unroll
                for (int nf_d = 0; nf_d < 4; ++nf_d) o_acc[mf_o][nf_d][r] *= f;
            }

        // ---- O += P @ V ----
#pragma unroll
        for (int s = 0; s < 2; ++s) {
            half8 pa0 = *reinterpret_cast<const half8*>(&Ps[w][0 * 16 + lr][s * 32 + lg * 8]);
            half8 pa1 = *reinterpret_cast<const half8*>(&Ps[w][1 * 16 + lr][s * 32 + lg * 8]);
#pragma unroll
            for (int nf_d = 0; nf_d < 4; ++nf_d) {
                half8 vb = *reinterpret_cast<const half8*>(&Vt[nf_d * 16 + lr][s * 32 + lg * 8]);
                o_acc[0][nf_d] = __builtin_amdgcn_mfma_f32_16x16x32_f16(pa0, vb, o_acc[0][nf_d], 0, 0, 0);
                o_acc[1][nf_d] = __builtin_amdgcn_mfma_f32_16x16x32_f16(pa1, vb, o_acc[1][nf_d], 0, 0, 0);
            }
        }
    }

    // ---- finalize (f16 heads out) ----
#pragma unroll
    for (int mf_o = 0; mf_o < 2; ++mf_o)
#pragma unroll
        for (int r = 0; r < 4; ++r) {
            float inv = 1.0f / __shfl(l_s[mf_o], lg * 4 + r);
            const int qrow = q0 + w * 32 + mf_o * 16 + lg * 4 + r;
#pragma unroll
            for (int nf_d = 0; nf_d < 4; ++nf_d)
                O[baseO + (size_t)qrow * PROJ + nf_d * 16 + lr] =
                    (_Float16)(o_acc[mf_o][nf_d][r] * inv);
        }
}

// ---------------------------------------------------------------------------
extern "C" void kernel_launch(void* const* d_in, const int* in_sizes, int n_in,
                              void* d_out, int out_size, void* d_ws, size_t ws_size,
                              hipStream_t stream) {
    const float* x  = (const float*)d_in[0];   // (BL, EMBED)
    const float* pW = (const float*)d_in[1];   // (EMBED, PROJ)
    const float* pb = (const float*)d_in[2];   // (PROJ)
    const float* Wq = (const float*)d_in[3];   // (PROJ, PROJ)
    const float* Wk = (const float*)d_in[4];
    const float* Wv = (const float*)d_in[5];
    const float* oW = (const float*)d_in[6];   // (PROJ, EMBED)
    float* out = (float*)d_out;                // (BL, EMBED) fp32

    _Float16* ws    = (_Float16*)d_ws;
    _Float16* p_h   = ws;                                  // BL x PROJ
    _Float16* qkv   = p_h + (size_t)BL * PROJ;             // BL x 1536
    _Float16* hd    = qkv + (size_t)BL * QKVN;             // BL x PROJ
    _Float16* pWt   = hd + (size_t)BL * PROJ;              // PROJ x EMBED
    _Float16* qkvWt = pWt + (size_t)PROJ * EMBED;          // 1536 x PROJ
    _Float16* oWt   = qkvWt + (size_t)QKVN * PROJ;         // EMBED x PROJ

    dim3 blk(256);

    // ---- weight prep (transpose + f16 convert; attn scale folded into Wq) ----
    trconv<<<dim3(PROJ / 64, EMBED / 64), blk, 0, stream>>>(pW, pWt, EMBED, PROJ, 1.0f);
    trconv<<<dim3(PROJ / 64, PROJ / 64), blk, 0, stream>>>(Wq, qkvWt, PROJ, PROJ, 0.125f);
    trconv<<<dim3(PROJ / 64, PROJ / 64), blk, 0, stream>>>(Wk, qkvWt + (size_t)PROJ * PROJ, PROJ, PROJ, 1.0f);
    trconv<<<dim3(PROJ / 64, PROJ / 64), blk, 0, stream>>>(Wv, qkvWt + (size_t)2 * PROJ * PROJ, PROJ, PROJ, 1.0f);
    trconv<<<dim3(EMBED / 64, PROJ / 64), blk, 0, stream>>>(oW, oWt, PROJ, EMBED, 1.0f);

    // ---- p = relu(x @ pW + b), f16 out ----
    gemm_mfma<1, 1, 0><<<dim3(PROJ / 128, BL / 64), blk, 0, stream>>>(
        (const void*)x, pWt, pb, (void*)p_h, BL, PROJ, EMBED);

    // ---- fused q|k|v = p @ [Wq|Wk|Wv], f16 out ----
    gemm_mfma<0, 0, 0><<<dim3(QKVN / 128, BL / 64), blk, 0, stream>>>(
        (const void*)p_h, qkvWt, nullptr, (void*)qkv, BL, QKVN, PROJ);

    // ---- attention ----
    attn_mfma<<<dim3(SEQ / 128, NHEADS, BATCH), blk, 0, stream>>>(
        qkv, qkv + PROJ, qkv + 2 * PROJ, hd);

    // ---- out = heads @ oW, fp32 out ----
    gemm_mfma<0, 0, 1><<<dim3(EMBED / 128, BL / 64), blk, 0, stream>>>(
        (const void*)hd, oWt, nullptr, (void*)out, BL, EMBED, PROJ);
}

// Round 5
// 121.810 us; speedup vs baseline: 5.1848x; 1.1250x over previous
//
#include <hip/hip_runtime.h>
#include <math.h>

#define BATCH 2
#define SEQ 2048
#define BL (BATCH * SEQ)      // 4096
#define EMBED 1024
#define PROJ 512
#define NHEADS 8
#define HDIM 64
#define QKVN (3 * PROJ)       // 1536 fused q|k|v columns

typedef _Float16 half8 __attribute__((ext_vector_type(8)));
typedef float floatx4 __attribute__((ext_vector_type(4)));

// ---------------------------------------------------------------------------
// Weight prep: dst[n][k] = (f16)(src[k][n] * scale)   (transpose + convert)
// ---------------------------------------------------------------------------
__global__ __launch_bounds__(256) void trconv(const float* __restrict__ src,
                                              _Float16* __restrict__ dst,
                                              int K, int N, float scale) {
    __shared__ float tile[64][65];
    const int t  = threadIdx.x;
    const int n0 = blockIdx.x * 64;
    const int k0 = blockIdx.y * 64;
    const int tx = t & 63;
    const int ty = t >> 6;   // 0..3
#pragma unroll
    for (int i = 0; i < 16; ++i) {
        int k = ty * 16 + i;
        tile[k][tx] = src[(size_t)(k0 + k) * N + n0 + tx];
    }
    __syncthreads();
#pragma unroll
    for (int i = 0; i < 16; ++i) {
        int n = ty * 16 + i;
        dst[(size_t)(n0 + n) * K + k0 + tx] = (_Float16)(tile[tx][n] * scale);
    }
}

// ---------------------------------------------------------------------------
// V pre-transpose: v (f16, token-major rows stride QKVN, head h cols 64)
//   -> vt[b][h][d][SEQ]  (f16)
// One 64x64 tile per block: grid (SEQ/64, NHEADS, BATCH).
// ---------------------------------------------------------------------------
__global__ __launch_bounds__(256) void trans_v(const _Float16* __restrict__ v,
                                               _Float16* __restrict__ vt) {
    __shared__ _Float16 tile[64][72];
    const int t  = threadIdx.x;
    const int t0 = blockIdx.x * 64;       // token tile (within batch)
    const int h  = blockIdx.y;
    const int b  = blockIdx.z;
    {
        const int r = t >> 2, c0 = (t & 3) * 16;
        const _Float16* src = v + (size_t)(b * SEQ + t0 + r) * QKVN + h * HDIM + c0;
        *reinterpret_cast<half8*>(&tile[r][c0])     = *reinterpret_cast<const half8*>(src);
        *reinterpret_cast<half8*>(&tile[r][c0 + 8]) = *reinterpret_cast<const half8*>(src + 8);
    }
    __syncthreads();
    {
        const int c = t >> 2, k0 = (t & 3) * 16;
        half8 o1, o2;
#pragma unroll
        for (int i = 0; i < 8; ++i) { o1[i] = tile[k0 + i][c]; o2[i] = tile[k0 + 8 + i][c]; }
        _Float16* dst = vt + ((size_t)(b * NHEADS + h) * HDIM + c) * SEQ + t0 + k0;
        *reinterpret_cast<half8*>(dst)     = o1;
        *reinterpret_cast<half8*>(dst + 8) = o2;
    }
}

// ---------------------------------------------------------------------------
// f16 MFMA GEMM: C[M][N] = A[M][K] @ Bt[N][K]^T (+bias, relu), fp32 accum.
// Block tile 64(M) x 128(N), BK=32, 256 threads = 4 waves (2x2 of 32x64).
// ---------------------------------------------------------------------------
template <int A_F32, int BIASRELU, int C_F32>
__global__ __launch_bounds__(256) void gemm_mfma(const void* __restrict__ Ap,
                                                 const _Float16* __restrict__ Bt,
                                                 const float* __restrict__ bias,
                                                 void* __restrict__ Cp,
                                                 int M, int N, int K) {
    __shared__ _Float16 Ah[64][40];
    __shared__ _Float16 Bh[128][40];

    const int t  = threadIdx.x;
    const int w  = t >> 6;
    const int l  = t & 63;
    const int lr = l & 15;
    const int lg = l >> 4;
    const int bm = blockIdx.y * 64;
    const int bn = blockIdx.x * 128;
    const int wr = w >> 1;
    const int wc = w & 1;

    const int ar = t >> 2, ac = (t & 3) * 8;
    const int br = t >> 1, bc = (t & 1) * 16;

    floatx4 acc[2][4];
#pragma unroll
    for (int i = 0; i < 2; ++i)
#pragma unroll
        for (int j = 0; j < 4; ++j) acc[i][j] = (floatx4){0.f, 0.f, 0.f, 0.f};

    float4 af0, af1;
    half8 areg, breg0, breg1;

    const float* Af = (const float*)Ap;
    const _Float16* Ah16 = (const _Float16*)Ap;

    if (A_F32) {
        af0 = *reinterpret_cast<const float4*>(&Af[(size_t)(bm + ar) * K + ac]);
        af1 = *reinterpret_cast<const float4*>(&Af[(size_t)(bm + ar) * K + ac + 4]);
    } else {
        areg = *reinterpret_cast<const half8*>(&Ah16[(size_t)(bm + ar) * K + ac]);
    }
    breg0 = *reinterpret_cast<const half8*>(&Bt[(size_t)(bn + br) * K + bc]);
    breg1 = *reinterpret_cast<const half8*>(&Bt[(size_t)(bn + br) * K + bc + 8]);

    for (int kt = 0; kt < K; kt += 32) {
        if (A_F32) {
            half8 hcv;
            hcv[0] = (_Float16)af0.x; hcv[1] = (_Float16)af0.y;
            hcv[2] = (_Float16)af0.z; hcv[3] = (_Float16)af0.w;
            hcv[4] = (_Float16)af1.x; hcv[5] = (_Float16)af1.y;
            hcv[6] = (_Float16)af1.z; hcv[7] = (_Float16)af1.w;
            *reinterpret_cast<half8*>(&Ah[ar][ac]) = hcv;
        } else {
            *reinterpret_cast<half8*>(&Ah[ar][ac]) = areg;
        }
        *reinterpret_cast<half8*>(&Bh[br][bc])     = breg0;
        *reinterpret_cast<half8*>(&Bh[br][bc + 8]) = breg1;
        __syncthreads();

        if (kt + 32 < K) {
            if (A_F32) {
                af0 = *reinterpret_cast<const float4*>(&Af[(size_t)(bm + ar) * K + kt + 32 + ac]);
                af1 = *reinterpret_cast<const float4*>(&Af[(size_t)(bm + ar) * K + kt + 32 + ac + 4]);
            } else {
                areg = *reinterpret_cast<const half8*>(&Ah16[(size_t)(bm + ar) * K + kt + 32 + ac]);
            }
            breg0 = *reinterpret_cast<const half8*>(&Bt[(size_t)(bn + br) * K + kt + 32 + bc]);
            breg1 = *reinterpret_cast<const half8*>(&Bt[(size_t)(bn + br) * K + kt + 32 + bc + 8]);
        }

        half8 afr[2], bfr[4];
#pragma unroll
        for (int mf = 0; mf < 2; ++mf)
            afr[mf] = *reinterpret_cast<const half8*>(&Ah[wr * 32 + mf * 16 + lr][lg * 8]);
#pragma unroll
        for (int nf = 0; nf < 4; ++nf)
            bfr[nf] = *reinterpret_cast<const half8*>(&Bh[wc * 64 + nf * 16 + lr][lg * 8]);
#pragma unroll
        for (int mf = 0; mf < 2; ++mf)
#pragma unroll
            for (int nf = 0; nf < 4; ++nf)
                acc[mf][nf] = __builtin_amdgcn_mfma_f32_16x16x32_f16(afr[mf], bfr[nf], acc[mf][nf], 0, 0, 0);

        __syncthreads();
    }

#pragma unroll
    for (int mf = 0; mf < 2; ++mf)
#pragma unroll
        for (int nf = 0; nf < 4; ++nf) {
            const int n = bn + wc * 64 + nf * 16 + lr;
            float bs = 0.f;
            if (BIASRELU) bs = bias[n];
#pragma unroll
            for (int r = 0; r < 4; ++r) {
                const int m = bm + wr * 32 + mf * 16 + lg * 4 + r;
                float v = acc[mf][nf][r];
                if (BIASRELU) v = fmaxf(v + bs, 0.f);
                if (C_F32)
                    ((float*)Cp)[(size_t)m * N + n] = v;
                else
                    ((_Float16*)Cp)[(size_t)m * N + n] = (_Float16)v;
            }
        }
}

// ---------------------------------------------------------------------------
// f16-MFMA flash attention v2.
// Q,K f16 rows stride QKVN; V pre-transposed vt[b][h][d][SEQ].
// Block: (b, h, 64 q rows), 4 waves x 16 q rows. KV tile = 64.
// Register prefetch of next K/V tile overlaps compute (T14).
// 2 barriers per tile; Ps is wave-private (no barrier).
// ---------------------------------------------------------------------------
__global__ __launch_bounds__(256) void attn_mfma(const _Float16* __restrict__ Q,
                                                 const _Float16* __restrict__ K,
                                                 const _Float16* __restrict__ Vt,
                                                 _Float16* __restrict__ O) {
    __shared__ _Float16 Ks[64][72];      // [kv][d]
    __shared__ _Float16 Vs[64][72];      // [d][kv]
    __shared__ _Float16 Ps[4][16][72];   // per-wave P: [q_local][kv]

    const int t  = threadIdx.x;
    const int w  = t >> 6;
    const int l  = t & 63;
    const int lr = l & 15;
    const int lg = l >> 4;

    const int q0 = blockIdx.x * 64;
    const int h  = blockIdx.y;
    const int b  = blockIdx.z;
    const size_t base  = (size_t)b * SEQ * QKVN + (size_t)h * HDIM;
    const size_t vbase = (size_t)(b * NHEADS + h) * HDIM * SEQ;
    const size_t baseO = (size_t)b * SEQ * PROJ + (size_t)h * HDIM;

    // ---- Q fragments (B-operand layout), 16 q rows per wave ----
    half8 qf[2];
#pragma unroll
    for (int s = 0; s < 2; ++s) {
        const int qrow = q0 + w * 16 + lr;
        qf[s] = *reinterpret_cast<const half8*>(
            &Q[base + (size_t)qrow * QKVN + s * 32 + lg * 8]);
    }

    floatx4 o_acc[4];
#pragma unroll
    for (int j = 0; j < 4; ++j) o_acc[j] = (floatx4){0.f, 0.f, 0.f, 0.f};

    float m_s = -1e30f;
    float l_s = 0.f;

    // staging: thread t covers row t>>2, 16 elems at (t&3)*16
    const int rkv = t >> 2;
    const int d0  = (t & 3) * 16;

    // ---- initial prefetch (tile 0) ----
    half8 ka0, ka1, va0, va1;
    {
        const _Float16* kp = K + base + (size_t)rkv * QKVN + d0;
        ka0 = *reinterpret_cast<const half8*>(kp);
        ka1 = *reinterpret_cast<const half8*>(kp + 8);
        const _Float16* vp = Vt + vbase + (size_t)rkv * SEQ + d0;
        va0 = *reinterpret_cast<const half8*>(vp);
        va1 = *reinterpret_cast<const half8*>(vp + 8);
    }

    for (int kt = 0; kt < SEQ; kt += 64) {
        // ---- write staged regs to LDS (b128, conflict-light) ----
        *reinterpret_cast<half8*>(&Ks[rkv][d0])     = ka0;
        *reinterpret_cast<half8*>(&Ks[rkv][d0 + 8]) = ka1;
        *reinterpret_cast<half8*>(&Vs[rkv][d0])     = va0;
        *reinterpret_cast<half8*>(&Vs[rkv][d0 + 8]) = va1;
        __syncthreads();

        // ---- prefetch next tile while computing this one ----
        if (kt + 64 < SEQ) {
            const _Float16* kp = K + base + (size_t)(kt + 64 + rkv) * QKVN + d0;
            ka0 = *reinterpret_cast<const half8*>(kp);
            ka1 = *reinterpret_cast<const half8*>(kp + 8);
            const _Float16* vp = Vt + vbase + (size_t)rkv * SEQ + kt + 64 + d0;
            va0 = *reinterpret_cast<const half8*>(vp);
            va1 = *reinterpret_cast<const half8*>(vp + 8);
        }

        // ---- S^T = K @ Q^T ----
        floatx4 stv[4];
#pragma unroll
        for (int i = 0; i < 4; ++i) stv[i] = (floatx4){0.f, 0.f, 0.f, 0.f};
#pragma unroll
        for (int s = 0; s < 2; ++s)
#pragma unroll
            for (int mf = 0; mf < 4; ++mf) {
                half8 kfr = *reinterpret_cast<const half8*>(&Ks[mf * 16 + lr][s * 32 + lg * 8]);
                stv[mf] = __builtin_amdgcn_mfma_f32_16x16x32_f16(kfr, qf[s], stv[mf], 0, 0, 0);
            }

        // ---- online softmax (lane owns kv-column slice for q = lr) ----
        float tm = -1e30f;
#pragma unroll
        for (int mf = 0; mf < 4; ++mf)
#pragma unroll
            for (int r = 0; r < 4; ++r) tm = fmaxf(tm, stv[mf][r]);
        tm = fmaxf(tm, __shfl_xor(tm, 16));
        tm = fmaxf(tm, __shfl_xor(tm, 32));
        float mn = fmaxf(m_s, tm);
        float fscale = __expf(m_s - mn);
        m_s = mn;
        float sum = 0.f;
#pragma unroll
        for (int mf = 0; mf < 4; ++mf)
#pragma unroll
            for (int r = 0; r < 4; ++r) {
                float p = __expf(stv[mf][r] - mn);
                stv[mf][r] = p;
                sum += p;
            }
        sum += __shfl_xor(sum, 16);
        sum += __shfl_xor(sum, 32);
        l_s = l_s * fscale + sum;

        // ---- P -> wave-private LDS (PV A-layout) ----
#pragma unroll
        for (int mf = 0; mf < 4; ++mf)
#pragma unroll
            for (int rp = 0; rp < 2; ++rp) {
                union { _Float16 hh[2]; unsigned int u; } pk;
                pk.hh[0] = (_Float16)stv[mf][2 * rp];
                pk.hh[1] = (_Float16)stv[mf][2 * rp + 1];
                *reinterpret_cast<unsigned int*>(
                    &Ps[w][lr][mf * 16 + lg * 4 + rp * 2]) = pk.u;
            }

        // ---- rescale O ----
#pragma unroll
        for (int r = 0; r < 4; ++r) {
            float f = __shfl(fscale, lg * 4 + r);
#pragma unroll
            for (int nf = 0; nf < 4; ++nf) o_acc[nf][r] *= f;
        }

        // ---- O += P @ V  (B-frag directly from transposed Vs) ----
#pragma unroll
        for (int s = 0; s < 2; ++s) {
            half8 pa = *reinterpret_cast<const half8*>(&Ps[w][lr][s * 32 + lg * 8]);
#pragma unroll
            for (int nf = 0; nf < 4; ++nf) {
                half8 vb = *reinterpret_cast<const half8*>(&Vs[nf * 16 + lr][s * 32 + lg * 8]);
                o_acc[nf] = __builtin_amdgcn_mfma_f32_16x16x32_f16(pa, vb, o_acc[nf], 0, 0, 0);
            }
        }

        __syncthreads();  // all waves done reading Ks/Vs before next staging write
    }

    // ---- finalize (f16 heads out) ----
#pragma unroll
    for (int r = 0; r < 4; ++r) {
        float inv = 1.0f / __shfl(l_s, lg * 4 + r);
        const int qrow = q0 + w * 16 + lg * 4 + r;
#pragma unroll
        for (int nf = 0; nf < 4; ++nf)
            O[baseO + (size_t)qrow * PROJ + nf * 16 + lr] =
                (_Float16)(o_acc[nf][r] * inv);
    }
}

// ---------------------------------------------------------------------------
extern "C" void kernel_launch(void* const* d_in, const int* in_sizes, int n_in,
                              void* d_out, int out_size, void* d_ws, size_t ws_size,
                              hipStream_t stream) {
    const float* x  = (const float*)d_in[0];   // (BL, EMBED)
    const float* pW = (const float*)d_in[1];   // (EMBED, PROJ)
    const float* pb = (const float*)d_in[2];   // (PROJ)
    const float* Wq = (const float*)d_in[3];   // (PROJ, PROJ)
    const float* Wk = (const float*)d_in[4];
    const float* Wv = (const float*)d_in[5];
    const float* oW = (const float*)d_in[6];   // (PROJ, EMBED)
    float* out = (float*)d_out;                // (BL, EMBED) fp32

    _Float16* ws    = (_Float16*)d_ws;
    _Float16* p_h   = ws;                                  // BL x PROJ
    _Float16* qkv   = p_h + (size_t)BL * PROJ;             // BL x 1536
    _Float16* hd    = qkv + (size_t)BL * QKVN;             // BL x PROJ
    _Float16* pWt   = hd + (size_t)BL * PROJ;              // PROJ x EMBED
    _Float16* qkvWt = pWt + (size_t)PROJ * EMBED;          // 1536 x PROJ
    _Float16* oWt   = qkvWt + (size_t)QKVN * PROJ;         // EMBED x PROJ
    _Float16* vtb   = oWt + (size_t)EMBED * PROJ;          // B*H*HDIM x SEQ

    dim3 blk(256);

    // ---- weight prep (transpose + f16 convert; attn scale folded into Wq) ----
    trconv<<<dim3(PROJ / 64, EMBED / 64), blk, 0, stream>>>(pW, pWt, EMBED, PROJ, 1.0f);
    trconv<<<dim3(PROJ / 64, PROJ / 64), blk, 0, stream>>>(Wq, qkvWt, PROJ, PROJ, 0.125f);
    trconv<<<dim3(PROJ / 64, PROJ / 64), blk, 0, stream>>>(Wk, qkvWt + (size_t)PROJ * PROJ, PROJ, PROJ, 1.0f);
    trconv<<<dim3(PROJ / 64, PROJ / 64), blk, 0, stream>>>(Wv, qkvWt + (size_t)2 * PROJ * PROJ, PROJ, PROJ, 1.0f);
    trconv<<<dim3(EMBED / 64, PROJ / 64), blk, 0, stream>>>(oW, oWt, PROJ, EMBED, 1.0f);

    // ---- p = relu(x @ pW + b), f16 out ----
    gemm_mfma<1, 1, 0><<<dim3(PROJ / 128, BL / 64), blk, 0, stream>>>(
        (const void*)x, pWt, pb, (void*)p_h, BL, PROJ, EMBED);

    // ---- fused q|k|v = p @ [Wq|Wk|Wv], f16 out ----
    gemm_mfma<0, 0, 0><<<dim3(QKVN / 128, BL / 64), blk, 0, stream>>>(
        (const void*)p_h, qkvWt, nullptr, (void*)qkv, BL, QKVN, PROJ);

    // ---- pre-transpose V per head: vt[b][h][d][SEQ] ----
    trans_v<<<dim3(SEQ / 64, NHEADS, BATCH), blk, 0, stream>>>(qkv + 2 * PROJ, vtb);

    // ---- attention ----
    attn_mfma<<<dim3(SEQ / 64, NHEADS, BATCH), blk, 0, stream>>>(
        qkv, qkv + PROJ, vtb, hd);

    // ---- out = heads @ oW, fp32 out ----
    gemm_mfma<0, 0, 1><<<dim3(EMBED / 128, BL / 64), blk, 0, stream>>>(
        (const void*)hd, oWt, nullptr, (void*)out, BL, EMBED, PROJ);
}